// Round 6
// baseline (647.941 us; speedup 1.0000x reference)
//
#include <hip/hip_runtime.h>
#include <cstdint>
#include <cstddef>
#include <math.h>

#define LC 1.44269504088896340736f   // log2(e)

__device__ __forceinline__ float rl_(float v, int k) {
    return __int_as_float(__builtin_amdgcn_readlane(__float_as_int(v), k));
}
__device__ __forceinline__ float bp_(float v, int addr4) {
    return __int_as_float(__builtin_amdgcn_ds_bpermute(addr4, __float_as_int(v)));
}
#define SZ_(v, pat) __int_as_float(__builtin_amdgcn_ds_swizzle(__float_as_int(v), (pat)))

__device__ __forceinline__ float sigm_(float u) {
    return __fdividef(1.f, 1.f + exp2f(-LC * u));
}
__device__ __forceinline__ float tanh_(float u) {
    return fmaf(-2.f, __fdividef(1.f, 1.f + exp2f((2.f * LC) * u)), 1.f);
}

// x element E (0..71) of current 4-step window from two lane-mapped banks
#define XEL(B0, B1, E) ((E) < 64 ? rl_((B0), (E)) : rl_((B1), (E) - 64))

// One fused iteration: GRU step t = t8+S, LSTM step u = t8+S-4.
// Ring slots: write (S+3)&3 = step t-1 proj; read S&3 = step u proj.
#define STEP(S, B0, B1) {                                                   \
    const bool lok = ((S) >= 4) || (t8 > 0);                                \
    const float xlv = rp[(S) & 3], xl2v = rs[(S) & 3];                      \
    /* G h-dots (+ LSTM secondary x-proj on lanes 54..61) */                \
    float aA0 = bA, aA1 = 0.f, aP0 = bP, aP1 = 0.f;                         \
    _Pragma("unroll")                                                       \
    for (int k = 0; k < 18; k += 2) {                                       \
        const float s0 = rl_(myh, k), s1 = rl_(myh, k + 1);                 \
        aA0 = fmaf(w1[k], s0, aA0); aA1 = fmaf(w1[k+1], s1, aA1);           \
        aP0 = fmaf(w2[k], s0, aP0); aP1 = fmaf(w2[k+1], s1, aP1);           \
    }                                                                       \
    const float haf = aA0 + aA1;                                            \
    rs[((S) + 3) & 3] = haf;                                                \
    rp[((S) + 3) & 3] = aP0 + aP1;                                          \
    /* G x-dot */                                                           \
    float xa0 = bX, xa1 = 0.f;                                              \
    _Pragma("unroll")                                                       \
    for (int k = 0; k < 18; k += 2) {                                       \
        xa0 = fmaf(w3[k],   XEL(B0, B1, ((S) & 3) * 18 + k),     xa0);      \
        xa1 = fmaf(w3[k+1], XEL(B0, B1, ((S) & 3) * 18 + k + 1), xa1);      \
    }                                                                       \
    const float xaf = xa0 + xa1;                                            \
    /* L h-dots */                                                          \
    float aB0 = bB, aB1 = 0.f, aS0 = bS, aS1 = 0.f;                         \
    _Pragma("unroll")                                                       \
    for (int k = 0; k < 18; k += 2) {                                       \
        const float t0 = rl_(myhl, k), t1 = rl_(myhl, k + 1);               \
        aB0 = fmaf(w4[k], t0, aB0); aB1 = fmaf(w4[k+1], t1, aB1);           \
        aS0 = fmaf(w5[k], t0, aS0); aS1 = fmaf(w5[k+1], t1, aS1);           \
    }                                                                       \
    /* G nonlinear */                                                       \
    const float sg = sigm_(xaf + haf);                                      \
    const float rv = bp_(sg, i3gb);                                         \
    const float tn = tanh_(fmaf(rv, haf, xaf));                             \
    const float zz = bp_(sg, i1b);                                          \
    const float nn = bp_(tn, i2b);                                          \
    myh = fmaf(zz, myh - nn, nn);                                           \
    /* L nonlinear */                                                       \
    const float a3 = fmaf(Aa, __fdividef(1.f, 1.f + exp2f(-kl * (xlv + aB0 + aB1))), Bb); \
    const float a4 = sigm_(xl2v + aS0 + aS1);                               \
    const float ff = bp_(a3, i1b);                                          \
    const float gg = bp_(a3, i2b);                                          \
    const float oa = bp_(a3, i3lb);                                         \
    const float ob = bp_(a4, i4b);                                          \
    const float oo = (lane < 10) ? oa : ob;                                 \
    const float cn = fmaf(ff, myc, a3 * gg);                                \
    myc = lok ? cn : myc;                                                   \
    myhl = oo * tanh_(myc);                                                 \
    float fv = fcw * myhl;                                                  \
    fv += SZ_(fv, 0x041F); fv += SZ_(fv, 0x081F);                           \
    fv += SZ_(fv, 0x101F); fv += SZ_(fv, 0x201F); fv += SZ_(fv, 0x401F);    \
    const float ov = fv + fcbv;                                             \
    if (((S) & 3) == 0) o0 = ov;                                            \
    else if (((S) & 3) == 1) o1 = ov;                                       \
    else if (((S) & 3) == 2) o2 = ov;                                       \
    else {                                                                  \
        o3 = ov;                                                            \
        if ((S) == 7 || t8 > 0) {                                           \
            if (lane == 0) {                                                \
                float4 vv = make_float4(o0, o1, o2, o3);                    \
                *reinterpret_cast<float4*>(outp + t8 + (S) - 7) = vv;       \
            }                                                               \
        }                                                                   \
    }                                                                       \
}

// Epilogue LSTM-only step: u = 1020+SL, slot SL
#define LSTEP(SL) {                                                         \
    const float xlv = rp[(SL)], xl2v = rs[(SL)];                            \
    float aB0 = bB, aB1 = 0.f, aS0 = bS, aS1 = 0.f;                         \
    _Pragma("unroll")                                                       \
    for (int k = 0; k < 18; k += 2) {                                       \
        const float t0 = rl_(myhl, k), t1 = rl_(myhl, k + 1);               \
        aB0 = fmaf(w4[k], t0, aB0); aB1 = fmaf(w4[k+1], t1, aB1);           \
        aS0 = fmaf(w5[k], t0, aS0); aS1 = fmaf(w5[k+1], t1, aS1);           \
    }                                                                       \
    const float a3 = fmaf(Aa, __fdividef(1.f, 1.f + exp2f(-kl * (xlv + aB0 + aB1))), Bb); \
    const float a4 = sigm_(xl2v + aS0 + aS1);                               \
    const float ff = bp_(a3, i1b);                                          \
    const float gg = bp_(a3, i2b);                                          \
    const float oa = bp_(a3, i3lb);                                         \
    const float ob = bp_(a4, i4b);                                          \
    const float oo = (lane < 10) ? oa : ob;                                 \
    myc = fmaf(ff, myc, a3 * gg);                                           \
    myhl = oo * tanh_(myc);                                                 \
    float fv = fcw * myhl;                                                  \
    fv += SZ_(fv, 0x041F); fv += SZ_(fv, 0x081F);                           \
    fv += SZ_(fv, 0x101F); fv += SZ_(fv, 0x201F); fv += SZ_(fv, 0x401F);    \
    const float ov = fv + fcbv;                                             \
    if ((SL) == 0) o0 = ov; else if ((SL) == 1) o1 = ov;                    \
    else if ((SL) == 2) o2 = ov; else o3 = ov;                              \
    if ((SL) == 3 && lane == 0) {                                           \
        float4 vv = make_float4(o0, o1, o2, o3);                            \
        *reinterpret_cast<float4*>(outp + 1020) = vv;                       \
    }                                                                       \
}

__global__ __launch_bounds__(64, 1) void rnn_fused6(
    const float* __restrict__ x,
    const float* __restrict__ gWih, const float* __restrict__ gWhh,
    const float* __restrict__ gbih, const float* __restrict__ gbhh,
    const float* __restrict__ lWih, const float* __restrict__ lWhh,
    const float* __restrict__ lbih, const float* __restrict__ lbhh,
    const float* __restrict__ fcW, const float* __restrict__ fcb,
    float* __restrict__ out)
{
    const int lane = threadIdx.x;
    const int b    = blockIdx.x;
    const float* xbp  = x   + (size_t)b * (1024 * 18);
    float*       outp = out + (size_t)b * 1024;

    // lane roles: GRU gates r/z/n on lanes 0..53; LSTM secondary rows 64..71 on lanes 54..61
    const bool sec  = (lane >= 54) && (lane < 62);
    const int  rg   = (lane < 54) ? lane : 0;
    const int  rsec = sec ? (64 + lane - 54) : 0;

    float w1[18], w2[18], w3[18], w4[18], w5[18];
    #pragma unroll
    for (int k = 0; k < 18; k++) {
        w1[k] = (lane < 54) ? gWhh[rg * 18 + k] : (sec ? lWih[rsec * 18 + k] : 0.f);
        w2[k] = lWih[lane * 18 + k];                 // LSTM Wih rows 0..63
        w3[k] = (lane < 54) ? gWih[rg * 18 + k] : 0.f;
        w4[k] = lWhh[lane * 18 + k];                 // LSTM Whh rows 0..63
        w5[k] = sec ? lWhh[rsec * 18 + k] : 0.f;     // LSTM Whh rows 64..71
    }
    const float bA = (lane < 54) ? gbhh[rg] : (sec ? lbih[rsec] : 0.f);
    const float bP = lbih[lane];
    const float bX = (lane < 54) ? gbih[rg] : 0.f;
    const float bB = lbhh[lane];
    const float bS = sec ? lbhh[rsec] : 0.f;

    // bpermute byte addresses (loop-invariant)
    const int i1b  = ((lane + 18) & 63) << 2;   // z / f
    const int i2b  = ((lane + 36) & 63) << 2;   // n / g
    const int i3gb = ((lane + 28) & 63) << 2;   // r -> n-lane
    const int i3lb = ((lane + 54) & 63) << 2;   // o primary (rows 54..63 -> units 0..9)
    const int i4b  = ((lane + 44) & 63) << 2;   // o secondary (lanes 54..61 -> units 10..17)

    const bool  isg = (lane >= 36) && (lane < 54);  // LSTM g-gate lanes: tanh
    const float kl  = isg ? (2.f * LC) : LC;
    const float Aa  = isg ? 2.f : 1.f;
    const float Bb  = isg ? -1.f : 0.f;

    const float fcw  = (lane < 18) ? fcW[lane] : 0.f;
    const float fcbv = fcb[0];

    float myh = 0.f, myc = 0.f, myhl = 0.f;
    float rp[4] = {0.f, 0.f, 0.f, 0.f};
    float rs[4] = {0.f, 0.f, 0.f, 0.f};
    float o0 = 0.f, o1 = 0.f, o2 = 0.f, o3 = 0.f;

    // x banks: window A = steps t8..t8+3, window B = t8+4..t8+7 (72 floats each)
    float xA0 = xbp[lane];
    float xA1 = xbp[64 + (lane & 7)];
    float xB0 = xbp[72 + lane];
    float xB1 = xbp[72 + 64 + (lane & 7)];

    for (int t8 = 0; t8 < 1024; t8 += 8) {
        STEP(0, xA0, xA1)
        STEP(1, xA0, xA1)
        STEP(2, xA0, xA1)
        STEP(3, xA0, xA1)
        if (t8 + 8 < 1024) {            // prefetch next window A (steps t8+8..t8+11)
            const float* p = xbp + (size_t)(t8 + 8) * 18;
            xA0 = p[lane]; xA1 = p[64 + (lane & 7)];
        }
        STEP(4, xB0, xB1)
        STEP(5, xB0, xB1)
        STEP(6, xB0, xB1)
        STEP(7, xB0, xB1)
        if (t8 + 12 < 1024) {           // prefetch next window B (steps t8+12..t8+15)
            const float* p = xbp + (size_t)(t8 + 12) * 18;
            xB0 = p[lane]; xB1 = p[64 + (lane & 7)];
        }
    }

    // final LSTM x-proj for step 1023 (ring slot 3)
    {
        float aA0 = bA, aA1 = 0.f, aP0 = bP, aP1 = 0.f;
        #pragma unroll
        for (int k = 0; k < 18; k += 2) {
            const float s0 = rl_(myh, k), s1 = rl_(myh, k + 1);
            aA0 = fmaf(w1[k], s0, aA0); aA1 = fmaf(w1[k+1], s1, aA1);
            aP0 = fmaf(w2[k], s0, aP0); aP1 = fmaf(w2[k+1], s1, aP1);
        }
        rs[3] = aA0 + aA1;
        rp[3] = aP0 + aP1;
    }
    // LSTM tail u = 1020..1023
    LSTEP(0)
    LSTEP(1)
    LSTEP(2)
    LSTEP(3)
}

extern "C" void kernel_launch(void* const* d_in, const int* in_sizes, int n_in,
                              void* d_out, int out_size, void* d_ws, size_t ws_size,
                              hipStream_t stream)
{
    (void)d_ws; (void)ws_size; (void)in_sizes; (void)n_in; (void)out_size;
    const float* xx   = (const float*)d_in[0];
    const float* gWih = (const float*)d_in[1];
    const float* gWhh = (const float*)d_in[2];
    const float* gbih = (const float*)d_in[3];
    const float* gbhh = (const float*)d_in[4];
    const float* lWih = (const float*)d_in[5];
    const float* lWhh = (const float*)d_in[6];
    const float* lbih = (const float*)d_in[7];
    const float* lbhh = (const float*)d_in[8];
    const float* fcW  = (const float*)d_in[9];
    const float* fcb  = (const float*)d_in[10];
    float* outp = (float*)d_out;

    dim3 grid(1024), block(64);
    hipLaunchKernelGGL(rnn_fused6, grid, block, 0, stream,
                       xx, gWih, gWhh, gbih, gbhh,
                       lWih, lWhh, lbih, lbhh, fcW, fcb, outp);
}

// Round 7
// 571.866 us; speedup vs baseline: 1.1330x; 1.1330x over previous
//
#include <hip/hip_runtime.h>
#include <cstdint>
#include <cstddef>
#include <math.h>

#define LC 1.44269504088896340736f   // log2(e)

__device__ __forceinline__ float rl_(float v, int k) {
    return __int_as_float(__builtin_amdgcn_readlane(__float_as_int(v), k));
}
__device__ __forceinline__ float bp_(float v, int addr4) {
    return __int_as_float(__builtin_amdgcn_ds_bpermute(addr4, __float_as_int(v)));
}
#define SZ_(v, pat) __int_as_float(__builtin_amdgcn_ds_swizzle(__float_as_int(v), (pat)))

__device__ __forceinline__ float sigm_(float u) {
    return __fdividef(1.f, 1.f + exp2f(-LC * u));
}
__device__ __forceinline__ float tanh_(float u) {
    return fmaf(-2.f, __fdividef(1.f, 1.f + exp2f((2.f * LC) * u)), 1.f);
}
// 18-float block-uniform LDS row -> registers (broadcast reads, 16B-aligned rows)
__device__ __forceinline__ void ld18_(float* d, const float* s) {
    *(float4*)&d[0]  = *(const float4*)&s[0];
    *(float4*)&d[4]  = *(const float4*)&s[4];
    *(float4*)&d[8]  = *(const float4*)&s[8];
    *(float4*)&d[12] = *(const float4*)&s[12];
    d[16] = s[16]; d[17] = s[17];
}

// wave0: GRU recurrence (h in regs, readlane broadcast) + full LSTM input projection.
// wave1: LSTM recurrence (h_l in regs, readlane) + FC. Coupled ONLY via ring (lag 16).
__global__ __launch_bounds__(128, 2) void rnn_fused7(
    const float* __restrict__ x,
    const float* __restrict__ gWih, const float* __restrict__ gWhh,
    const float* __restrict__ gbih, const float* __restrict__ gbhh,
    const float* __restrict__ lWih, const float* __restrict__ lWhh,
    const float* __restrict__ lbih, const float* __restrict__ lbhh,
    const float* __restrict__ fcW, const float* __restrict__ fcb,
    float* __restrict__ out)
{
    const int tid  = threadIdx.x;
    const int wid  = tid >> 6;
    const int lane = tid & 63;
    const int b    = blockIdx.x;

    __shared__ __align__(16) float ring[32][80];   // LSTM input-proj ring (slot = step & 31)
    __shared__ __align__(16) float xs[2][8][20];   // staged x window (wave0-private)

    const float* xb   = x   + (size_t)b * (1024 * 18);
    float*       outp = out + (size_t)b * 1024;

    const bool sec  = (lane >= 54) && (lane < 62);
    const int  rsec = sec ? (64 + lane - 54) : 64;

    if (wid == 0) {
        // ---------------- wave0 ----------------
        const int rg = (lane < 54) ? lane : 0;     // GRU gate row (r:0..17, z:18..35, n:36..53)
        float w1[18], w2[18], wX[18];
        #pragma unroll
        for (int k = 0; k < 18; k++) {
            w1[k] = (lane < 54) ? gWhh[rg * 18 + k] : (sec ? lWih[rsec * 18 + k] : 0.f);
            w2[k] = lWih[lane * 18 + k];           // LSTM Wih rows 0..63 (primary)
            wX[k] = (lane < 54) ? gWih[rg * 18 + k] : 0.f;
        }
        const float bA = (lane < 54) ? gbhh[rg] : (sec ? lbih[rsec] : 0.f);
        const float bP = lbih[lane];
        const float bX = (lane < 54) ? gbih[rg] : 0.f;

        const int i1b = ((lane + 18) & 63) << 2;   // z_j -> lane j
        const int i2b = ((lane + 36) & 63) << 2;   // n_j -> lane j
        const int i3b = ((lane + 28) & 63) << 2;   // r_j -> n-lane 36+j

        float myh = 0.f;

        // x staging maps (window = 8 steps = 144 floats)
        const int j0 = lane, j1 = lane + 64, j2 = lane + 128;
        const int r0 = j0 / 18, c0 = j0 % 18;
        const int r1 = j1 / 18, c1 = j1 % 18;
        const int r2 = j2 / 18, c2 = j2 % 18;

        // prologue: land window 0, prefetch window 1
        float p0 = xb[j0], p1 = xb[j1], p2 = (lane < 16) ? xb[j2] : 0.f;
        xs[0][r0][c0] = p0; xs[0][r1][c1] = p1; if (lane < 16) xs[0][r2][c2] = p2;
        p0 = xb[144 + j0]; p1 = xb[144 + j1]; if (lane < 16) p2 = xb[144 + j2];

        for (int p = 0; p < 130; p++) {
            __syncthreads();
            if (p < 128) {
                if (p + 1 < 128) {                 // land window p+1 into other buffer
                    const int bu = (p + 1) & 1;
                    xs[bu][r0][c0] = p0; xs[bu][r1][c1] = p1; if (lane < 16) xs[bu][r2][c2] = p2;
                    if (p + 2 < 128) {             // prefetch window p+2
                        const float* xw = xb + (size_t)(p + 2) * 144;
                        p0 = xw[j0]; p1 = xw[j1]; if (lane < 16) p2 = xw[j2];
                    }
                }
                const float* xbase = &xs[p & 1][0][0];
                #pragma unroll 2
                for (int j = 0; j < 8; j++) {
                    const int t = p * 8 + j;
                    // loop1: readlane h[t-1]; GRU Whh (lanes<54) / LSTM-Wih-sec (54..61)
                    // plus LSTM Wih primary (all lanes)
                    float aA0 = bA, aA1 = 0.f, aP0 = bP, aP1 = 0.f;
                    #pragma unroll
                    for (int k = 0; k < 18; k += 2) {
                        const float s0 = rl_(myh, k), s1 = rl_(myh, k + 1);
                        aA0 = fmaf(w1[k],   s0, aA0); aA1 = fmaf(w1[k+1], s1, aA1);
                        aP0 = fmaf(w2[k],   s0, aP0); aP1 = fmaf(w2[k+1], s1, aP1);
                    }
                    const float ha = aA0 + aA1;
                    float* rw = &ring[(t - 1) & 31][0];      // proj of h[t-1] -> LSTM step t-1
                    rw[lane] = aP0 + aP1;                     // primary rows 0..63
                    if (sec) rw[64 + (lane - 54)] = ha;       // secondary rows 64..71
                    // GRU x-dot (broadcast LDS read)
                    float xr[18]; ld18_(xr, xbase + j * 20);
                    float xa0 = bX, xa1 = 0.f;
                    #pragma unroll
                    for (int k = 0; k < 18; k += 2) {
                        xa0 = fmaf(wX[k],   xr[k],   xa0);
                        xa1 = fmaf(wX[k+1], xr[k+1], xa1);
                    }
                    const float xa = xa0 + xa1;
                    // GRU nonlinear + update (h lives on lanes 0..17)
                    const float sg = sigm_(xa + ha);
                    const float rv = bp_(sg, i3b);
                    const float tn = tanh_(fmaf(rv, ha, xa));
                    const float zz = bp_(sg, i1b);
                    const float nn = bp_(tn, i2b);
                    const float hnew = fmaf(zz, myh - nn, nn);
                    myh = (lane < 18) ? hnew : myh;
                }
            } else if (p == 128) {
                // epilogue: LSTM input-proj for step 1023 from final h
                float aA0 = bA, aA1 = 0.f, aP0 = bP, aP1 = 0.f;
                #pragma unroll
                for (int k = 0; k < 18; k += 2) {
                    const float s0 = rl_(myh, k), s1 = rl_(myh, k + 1);
                    aA0 = fmaf(w1[k],   s0, aA0); aA1 = fmaf(w1[k+1], s1, aA1);
                    aP0 = fmaf(w2[k],   s0, aP0); aP1 = fmaf(w2[k+1], s1, aP1);
                }
                float* rw = &ring[1023 & 31][0];
                rw[lane] = aP0 + aP1;
                if (sec) rw[64 + (lane - 54)] = aA0 + aA1;
            }
        }
    } else {
        // ---------------- wave1 ----------------
        float w1[18], w2[18];
        #pragma unroll
        for (int k = 0; k < 18; k++) {
            w1[k] = lWhh[lane * 18 + k];                     // rows 0..63 (i,f,g,o0..9)
            w2[k] = sec ? lWhh[rsec * 18 + k] : 0.f;         // rows 64..71 (o10..17)
        }
        const float bB = lbhh[lane];
        const float bS = sec ? lbhh[rsec] : 0.f;

        const int i1b = ((lane + 18) & 63) << 2;   // f
        const int i2b = ((lane + 36) & 63) << 2;   // g
        const int i3b = ((lane + 54) & 63) << 2;   // o primary (units 0..9)
        const int i4b = ((lane + 44) & 63) << 2;   // o secondary (units 10..17 <- lanes 54..61)

        const bool  isg = (lane >= 36) && (lane < 54);       // g-gate rows: tanh
        const float kl  = isg ? (2.f * LC) : LC;
        const float Aa  = isg ? 2.f : 1.f;
        const float Bb  = isg ? -1.f : 0.f;

        const float fcw  = (lane < 18) ? fcW[lane] : 0.f;
        const float fcbv = fcb[0];

        float myc = 0.f, myhl = 0.f;
        float o0 = 0.f, o1 = 0.f, o2 = 0.f, o3 = 0.f;

        for (int p = 0; p < 130; p++) {
            __syncthreads();
            if (p >= 2) {
                #pragma unroll 2
                for (int j = 0; j < 8; j++) {
                    const int u = (p - 2) * 8 + j;
                    // readlane h_l[u-1]; Whh primary + secondary
                    float h0 = bB, h1 = 0.f, g0 = bS, g1 = 0.f;
                    #pragma unroll
                    for (int k = 0; k < 18; k += 2) {
                        const float t0 = rl_(myhl, k), t1 = rl_(myhl, k + 1);
                        h0 = fmaf(w1[k],   t0, h0); h1 = fmaf(w1[k+1], t1, h1);
                        g0 = fmaf(w2[k],   t0, g0); g1 = fmaf(w2[k+1], t1, g1);
                    }
                    const float* rr = &ring[u & 31][0];
                    const float xl  = rr[lane];
                    const float xl2 = rr[64 + ((lane - 54) & 7)];
                    const float a3 = fmaf(Aa, __fdividef(1.f, 1.f + exp2f(-kl * (xl + h0 + h1))), Bb);
                    const float a4 = sigm_(xl2 + g0 + g1);
                    const float ff = bp_(a3, i1b);
                    const float gg = bp_(a3, i2b);
                    const float oa = bp_(a3, i3b);
                    const float ob = bp_(a4, i4b);
                    const float oo = (lane < 10) ? oa : ob;
                    const float cn = fmaf(ff, myc, a3 * gg);   // a3 on lanes<18 = i-gate
                    myc  = cn;
                    myhl = oo * tanh_(cn);                     // valid on lanes 0..17
                    // FC (lanes >= 18 contribute 0)
                    float fv = fcw * myhl;
                    fv += SZ_(fv, 0x041F); fv += SZ_(fv, 0x081F);
                    fv += SZ_(fv, 0x101F); fv += SZ_(fv, 0x201F); fv += SZ_(fv, 0x401F);
                    const float ov = fv + fcbv;
                    const int sm = j & 3;
                    if (sm == 0) o0 = ov; else if (sm == 1) o1 = ov;
                    else if (sm == 2) o2 = ov; else o3 = ov;
                    if (sm == 3 && lane == 0) {
                        float4 vv; vv.x = o0; vv.y = o1; vv.z = o2; vv.w = o3;
                        *reinterpret_cast<float4*>(outp + u - 3) = vv;
                    }
                }
            }
        }
    }
}

extern "C" void kernel_launch(void* const* d_in, const int* in_sizes, int n_in,
                              void* d_out, int out_size, void* d_ws, size_t ws_size,
                              hipStream_t stream)
{
    (void)d_ws; (void)ws_size; (void)in_sizes; (void)n_in; (void)out_size;
    const float* xx   = (const float*)d_in[0];
    const float* gWih = (const float*)d_in[1];
    const float* gWhh = (const float*)d_in[2];
    const float* gbih = (const float*)d_in[3];
    const float* gbhh = (const float*)d_in[4];
    const float* lWih = (const float*)d_in[5];
    const float* lWhh = (const float*)d_in[6];
    const float* lbih = (const float*)d_in[7];
    const float* lbhh = (const float*)d_in[8];
    const float* fcW  = (const float*)d_in[9];
    const float* fcb  = (const float*)d_in[10];
    float* outp = (float*)d_out;

    dim3 grid(1024), block(128);
    hipLaunchKernelGGL(rnn_fused7, grid, block, 0, stream,
                       xx, gWih, gWhh, gbih, gbhh,
                       lWih, lWhh, lbih, lbhh, fcW, fcb, outp);
}

// Round 8
// 562.717 us; speedup vs baseline: 1.1515x; 1.0163x over previous
//
#include <hip/hip_runtime.h>
#include <cstdint>
#include <cstddef>
#include <math.h>

#define LC 1.44269504088896340736f   // log2(e)

__device__ __forceinline__ float rl_(float v, int k) {
    return __int_as_float(__builtin_amdgcn_readlane(__float_as_int(v), k));
}
__device__ __forceinline__ float bp_(float v, int addr4) {
    return __int_as_float(__builtin_amdgcn_ds_bpermute(addr4, __float_as_int(v)));
}
#define SZ_(v, pat) __int_as_float(__builtin_amdgcn_ds_swizzle(__float_as_int(v), (pat)))

__device__ __forceinline__ float sigm_(float u) {
    return __fdividef(1.f, 1.f + exp2f(-LC * u));
}
__device__ __forceinline__ float tanh_(float u) {
    return fmaf(-2.f, __fdividef(1.f, 1.f + exp2f((2.f * LC) * u)), 1.f);
}
__device__ __forceinline__ void ld18_(float* d, const float* s) {
    *(float4*)&d[0]  = *(const float4*)&s[0];
    *(float4*)&d[4]  = *(const float4*)&s[4];
    *(float4*)&d[8]  = *(const float4*)&s[8];
    *(float4*)&d[12] = *(const float4*)&s[12];
    d[16] = s[16]; d[17] = s[17];
}

// 4-wave pipeline per batch row:
//  G: GRU recurrence            (consumes xaR, produces hR)
//  P: LSTM input projection     (consumes hR lag 8, produces xlR)
//  L: LSTM recurrence + FC      (consumes xlR lag 16)
//  X: GRU input projection      (produces xaR 1 window ahead, stages x)
__global__ __launch_bounds__(256) void rnn_fused8(
    const float* __restrict__ x,
    const float* __restrict__ gWih, const float* __restrict__ gWhh,
    const float* __restrict__ gbih, const float* __restrict__ gbhh,
    const float* __restrict__ lWih, const float* __restrict__ lWhh,
    const float* __restrict__ lbih, const float* __restrict__ lbhh,
    const float* __restrict__ fcW, const float* __restrict__ fcb,
    float* __restrict__ out)
{
    const int tid  = threadIdx.x;
    const int wid  = tid >> 6;
    const int lane = tid & 63;
    const int b    = blockIdx.x;
    const int role = (wid + b) & 3;          // rotate roles across blocks -> SIMD balance

    __shared__ __align__(16) float xaR[16][64];   // GRU input proj ring (slot = t & 15)
    __shared__ __align__(16) float hR [16][64];   // GRU h ring
    __shared__ __align__(16) float xlR[16][80];   // LSTM input proj ring
    __shared__ __align__(16) float xst[2][8][20]; // staged x window (X-private)

    const float* xb   = x   + (size_t)b * (1024 * 18);
    float*       outp = out + (size_t)b * 1024;

    const bool sec  = (lane >= 54) && (lane < 62);
    const int  rg   = (lane < 54) ? lane : 0;
    const int  rsec = sec ? (64 + lane - 54) : 64;

    if (role == 3) {
        // ---------------- X: GRU input projection + x staging ----------------
        float wX[18];
        #pragma unroll
        for (int k = 0; k < 18; k++) wX[k] = (lane < 54) ? gWih[rg * 18 + k] : 0.f;
        const float bX = (lane < 54) ? gbih[rg] : 0.f;

        const int j0 = lane, j1 = lane + 64, j2 = lane + 128;
        const int r0 = j0 / 18, c0 = j0 % 18;
        const int r1 = j1 / 18, c1 = j1 % 18;
        const int r2 = j2 / 18, c2 = j2 % 18;

        // prologue: window 0 -> xst[0], xa for steps 0..7, prefetch window 1
        float p0 = xb[j0], p1 = xb[j1], p2 = (lane < 16) ? xb[j2] : 0.f;
        xst[0][r0][c0] = p0; xst[0][r1][c1] = p1; if (lane < 16) xst[0][r2][c2] = p2;
        __builtin_amdgcn_wave_barrier();
        #pragma unroll
        for (int j = 0; j < 8; j++) {
            float xr[18]; ld18_(xr, &xst[0][j][0]);
            float a0 = bX, a1 = 0.f;
            #pragma unroll
            for (int k = 0; k < 18; k += 2) { a0 = fmaf(wX[k], xr[k], a0); a1 = fmaf(wX[k+1], xr[k+1], a1); }
            xaR[j][lane] = a0 + a1;
        }
        p0 = xb[144 + j0]; p1 = xb[144 + j1]; if (lane < 16) p2 = xb[144 + j2];

        for (int p = 0; p < 130; p++) {
            __syncthreads();
            if (p <= 126) {
                const int bu = (p + 1) & 1;
                xst[bu][r0][c0] = p0; xst[bu][r1][c1] = p1; if (lane < 16) xst[bu][r2][c2] = p2;
                if (p + 2 <= 127) {
                    const float* xw = xb + (size_t)(p + 2) * 144;
                    p0 = xw[j0]; p1 = xw[j1]; if (lane < 16) p2 = xw[j2];
                }
                __builtin_amdgcn_wave_barrier();
                const int s1 = ((p + 1) * 8) & 15;
                #pragma unroll
                for (int j = 0; j < 8; j++) {
                    float xr[18]; ld18_(xr, &xst[bu][j][0]);
                    float a0 = bX, a1 = 0.f;
                    #pragma unroll
                    for (int k = 0; k < 18; k += 2) { a0 = fmaf(wX[k], xr[k], a0); a1 = fmaf(wX[k+1], xr[k+1], a1); }
                    xaR[s1 + j][lane] = a0 + a1;
                }
            }
        }
    } else if (role == 0) {
        // ---------------- G: GRU recurrence ----------------
        float wG[18];
        #pragma unroll
        for (int k = 0; k < 18; k++) wG[k] = (lane < 54) ? gWhh[rg * 18 + k] : 0.f;
        const float bG = (lane < 54) ? gbhh[rg] : 0.f;

        const int i1b = ((lane + 18) & 63) << 2;   // z_j -> lane j
        const int i2b = ((lane + 36) & 63) << 2;   // n_j -> lane j
        const int i3b = ((lane + 28) & 63) << 2;   // r_j -> n-lane 36+j

        float myh = 0.f;

        for (int p = 0; p < 130; p++) {
            __syncthreads();
            if (p <= 127) {
                const int s0 = (p * 8) & 15;
                #pragma unroll
                for (int j = 0; j < 8; j++) {
                    const float xa = xaR[s0 + j][lane];
                    float a0 = bG, a1 = 0.f;
                    #pragma unroll
                    for (int k = 0; k < 18; k += 2) {
                        const float s_0 = rl_(myh, k), s_1 = rl_(myh, k + 1);
                        a0 = fmaf(wG[k], s_0, a0); a1 = fmaf(wG[k+1], s_1, a1);
                    }
                    const float ha = a0 + a1;
                    const float sg = sigm_(xa + ha);
                    const float rv = bp_(sg, i3b);
                    const float tn = tanh_(fmaf(rv, ha, xa));
                    const float zz = bp_(sg, i1b);
                    const float nn = bp_(tn, i2b);
                    myh = fmaf(zz, myh - nn, nn);          // unconditional; lanes>=18 finite garbage
                    hR[s0 + j][lane] = myh;
                }
            }
        }
    } else if (role == 1) {
        // ---------------- P: LSTM input projection (lag 8) ----------------
        float wP[18], wS[18];
        #pragma unroll
        for (int k = 0; k < 18; k++) {
            wP[k] = lWih[lane * 18 + k];                     // rows 0..63
            wS[k] = sec ? lWih[rsec * 18 + k] : 0.f;         // rows 64..71
        }
        const float bP = lbih[lane];
        const float bS = sec ? lbih[rsec] : 0.f;

        for (int p = 0; p < 130; p++) {
            __syncthreads();
            if (p >= 1 && p <= 128) {
                const int s0 = ((p - 1) * 8) & 15;
                #pragma unroll
                for (int j = 0; j < 8; j++) {
                    const float hreg = hR[s0 + j][lane];     // lane k holds h[k] (k<18)
                    float a0 = bP, a1 = 0.f, c0 = bS, c1 = 0.f;
                    #pragma unroll
                    for (int k = 0; k < 18; k += 2) {
                        const float s_0 = rl_(hreg, k), s_1 = rl_(hreg, k + 1);
                        a0 = fmaf(wP[k], s_0, a0); a1 = fmaf(wP[k+1], s_1, a1);
                        c0 = fmaf(wS[k], s_0, c0); c1 = fmaf(wS[k+1], s_1, c1);
                    }
                    xlR[s0 + j][lane] = a0 + a1;
                    if (sec) xlR[s0 + j][64 + (lane - 54)] = c0 + c1;
                }
            }
        }
    } else {
        // ---------------- L: LSTM recurrence + FC (lag 16) ----------------
        float wL[18], wL2[18];
        #pragma unroll
        for (int k = 0; k < 18; k++) {
            wL[k]  = lWhh[lane * 18 + k];
            wL2[k] = sec ? lWhh[rsec * 18 + k] : 0.f;
        }
        const float bL  = lbhh[lane];
        const float bL2 = sec ? lbhh[rsec] : 0.f;

        const int i1b = ((lane + 18) & 63) << 2;   // f
        const int i2b = ((lane + 36) & 63) << 2;   // g
        const int i3b = ((lane + 54) & 63) << 2;   // o units 0..9
        const int i4b = ((lane + 44) & 63) << 2;   // o units 10..17 (from lanes 54..61)

        const bool  isg = (lane >= 36) && (lane < 54);
        const float kl  = isg ? (2.f * LC) : LC;
        const float Aa  = isg ? 2.f : 1.f;
        const float Bb  = isg ? -1.f : 0.f;

        const float fcw  = (lane < 18) ? fcW[lane] : 0.f;
        const float fcbv = fcb[0];

        float myc = 0.f, myhl = 0.f;
        float o0 = 0.f, o1 = 0.f, o2 = 0.f, o3 = 0.f;

        for (int p = 0; p < 130; p++) {
            __syncthreads();
            if (p >= 2) {
                const int base = (p - 2) * 8;
                const int s0   = base & 15;
                #pragma unroll
                for (int j = 0; j < 8; j++) {
                    const float xl  = xlR[s0 + j][lane];
                    const float xl2 = xlR[s0 + j][64 + ((lane - 54) & 7)];
                    float a0 = bL, a1 = 0.f, c0 = bL2, c1 = 0.f;
                    #pragma unroll
                    for (int k = 0; k < 18; k += 2) {
                        const float s_0 = rl_(myhl, k), s_1 = rl_(myhl, k + 1);
                        a0 = fmaf(wL[k], s_0, a0); a1 = fmaf(wL[k+1], s_1, a1);
                        c0 = fmaf(wL2[k], s_0, c0); c1 = fmaf(wL2[k+1], s_1, c1);
                    }
                    const float a3 = fmaf(Aa, __fdividef(1.f, 1.f + exp2f(-kl * (xl + a0 + a1))), Bb);
                    const float a4 = sigm_(xl2 + c0 + c1);
                    const float ff = bp_(a3, i1b);
                    const float gg = bp_(a3, i2b);
                    const float oa = bp_(a3, i3b);
                    const float ob = bp_(a4, i4b);
                    const float oo = (lane < 10) ? oa : ob;
                    myc  = fmaf(ff, myc, a3 * gg);         // a3 on lanes<18 = i-gate
                    myhl = oo * tanh_(myc);
                    float fv = fcw * myhl;
                    fv += SZ_(fv, 0x041F); fv += SZ_(fv, 0x081F);
                    fv += SZ_(fv, 0x101F); fv += SZ_(fv, 0x201F); fv += SZ_(fv, 0x401F);
                    const float ov = fv + fcbv;
                    if ((j & 3) == 0) o0 = ov; else if ((j & 3) == 1) o1 = ov;
                    else if ((j & 3) == 2) o2 = ov; else o3 = ov;
                    if ((j & 3) == 3 && lane == 0) {
                        float4 vv; vv.x = o0; vv.y = o1; vv.z = o2; vv.w = o3;
                        *reinterpret_cast<float4*>(outp + base + j - 3) = vv;
                    }
                }
            }
        }
    }
}

extern "C" void kernel_launch(void* const* d_in, const int* in_sizes, int n_in,
                              void* d_out, int out_size, void* d_ws, size_t ws_size,
                              hipStream_t stream)
{
    (void)d_ws; (void)ws_size; (void)in_sizes; (void)n_in; (void)out_size;
    const float* xx   = (const float*)d_in[0];
    const float* gWih = (const float*)d_in[1];
    const float* gWhh = (const float*)d_in[2];
    const float* gbih = (const float*)d_in[3];
    const float* gbhh = (const float*)d_in[4];
    const float* lWih = (const float*)d_in[5];
    const float* lWhh = (const float*)d_in[6];
    const float* lbih = (const float*)d_in[7];
    const float* lbhh = (const float*)d_in[8];
    const float* fcW  = (const float*)d_in[9];
    const float* fcb  = (const float*)d_in[10];
    float* outp = (float*)d_out;

    dim3 grid(1024), block(256);
    hipLaunchKernelGGL(rnn_fused8, grid, block, 0, stream,
                       xx, gWih, gWhh, gbih, gbhh,
                       lWih, lWhh, lbih, lbhh, fcW, fcb, outp);
}